// Round 5
// baseline (237.994 us; speedup 1.0000x reference)
//
#include <hip/hip_runtime.h>
#include <cstdint>
#include <cstddef>

#define N_COLS 4096
#define TPB 256
#define NCOPY 8
#define HSTR 12               // 8 copies + 4 pad words (48 B stride, 16B-aligned)
#define NHW (256 * HSTR)      // 3072 words (12 KB) per row-histogram
#define SURV_CAP 64

typedef float v4f __attribute__((ext_vector_type(4)));

__device__ __forceinline__ void store_nt(float4* p, const float4& v) {
    __builtin_nontemporal_store(*(const v4f*)&v, (v4f*)p);
}

// --- kernel 1: boost factors, double-precision exp rounded to fp32 ---
__global__ void boost_kernel(const float* __restrict__ dc,
                             const int* __restrict__ kp,
                             float* __restrict__ bf) {
    int i = blockIdx.x * blockDim.x + threadIdx.x;
    if (i < N_COLS) {
        float td = (float)kp[0] / (float)N_COLS;   // float32(k)/float32(n), like ref
        float arg = td - dc[i];                    // fp32 subtract, like ref
        bf[i] = (float)exp((double)arg);           // ~correctly-rounded fp32 exp
    }
}

__device__ __forceinline__ uint32_t orderable(uint32_t u) {
    return (u & 0x80000000u) ? ~u : (u | 0x80000000u);  // float order == uint order
}

// two rows per block; 16 boosted values per row per thread in registers
__global__ __launch_bounds__(TPB) void kwinner_kernel(
    const float* __restrict__ x, const float* __restrict__ bf,
    const int* __restrict__ kp, float* __restrict__ out, int rows)
{
    __shared__ uint32_t s_hist[2 * NHW];     // 24 KB, bin-major per row
    __shared__ uint32_t s_cnt[256];          // fallback scan buffer
    __shared__ uint32_t s_cand[2][SURV_CAP];
    __shared__ uint32_t s_m2[2];

    const int tid  = threadIdx.x;
    const int lane = tid & 63;
    const uint32_t copy = (uint32_t)(tid & (NCOPY - 1));
    const int rowA = 2 * (int)blockIdx.x;
    const int rowB = rowA + 1;
    const bool validB = rowB < rows;
    const float4* xrA = (const float4*)(x + (size_t)rowA * N_COLS);
    const float4* xrB = (const float4*)(x + (size_t)(validB ? rowB : rowA) * N_COLS);
    const float4* br  = (const float4*)bf;
    float4* orowA = (float4*)(out + (size_t)rowA * N_COLS);
    float4* orowB = (float4*)(out + (size_t)rowB * N_COLS);

    float xbA[16], xbB[16];
    #pragma unroll
    for (int j = 0; j < 4; ++j) {
        float4 b = br[tid + j * TPB];        // shared between both rows
        float4 a = xrA[tid + j * TPB];
        float4 c = xrB[tid + j * TPB];
        xbA[4*j+0] = a.x*b.x; xbA[4*j+1] = a.y*b.y;
        xbA[4*j+2] = a.z*b.z; xbA[4*j+3] = a.w*b.w;
        xbB[4*j+0] = c.x*b.x; xbB[4*j+1] = c.y*b.y;
        xbB[4*j+2] = c.z*b.z; xbB[4*j+3] = c.w*b.w;
    }

    // clear both histograms (vectorized) + survivor counters
    {
        uint4* h4 = (uint4*)s_hist;
        uint4 z; z.x = z.y = z.z = z.w = 0u;
        #pragma unroll
        for (int j = 0; j < 6; ++j) h4[tid + j * TPB] = z;   // 1536 uint4
    }
    if (tid < 2) s_m2[tid] = 0;
    __syncthreads();

    // single histogram pass per row over candidates >= T0, composite digit
    // d = min((bits>>16) - 0x3F80, 255): monotone for all floats >= 1.0.
    const float T0f = 1.10f;   // perf heuristic only; exactness guarded below
    #pragma unroll
    for (int e = 0; e < 16; ++e) {
        if (xbA[e] >= T0f) {
            uint32_t d = (__float_as_uint(xbA[e]) >> 16) - 0x3F80u;
            d = d > 255u ? 255u : d;
            atomicAdd(&s_hist[d * HSTR + copy], 1u);
        }
        if (xbB[e] >= T0f) {
            uint32_t d = (__float_as_uint(xbB[e]) >> 16) - 0x3F80u;
            d = d > 255u ? 255u : d;
            atomicAdd(&s_hist[NHW + d * HSTR + copy], 1u);
        }
    }
    __syncthreads();

    const uint32_t k = (uint32_t)kp[0];

    // fused copy-reduce + suffix-scan + digit pick, replicated on every wave
    auto scan_row = [&](const uint32_t* hist, uint32_t& remr) -> uint32_t {
        uint32_t vv[4];
        const uint32_t b0 = (uint32_t)lane * 4u;
        #pragma unroll
        for (int i = 0; i < 4; ++i) {
            uint4 a  = *(const uint4*)&hist[(b0 + i) * HSTR];
            uint4 b2 = *(const uint4*)&hist[(b0 + i) * HSTR + 4];
            vv[i] = a.x + a.y + a.z + a.w + b2.x + b2.y + b2.z + b2.w;
        }
        uint32_t s3 = vv[3], s2 = vv[2] + s3, s1 = vv[1] + s2, s0 = vv[0] + s1;
        uint32_t T = s0;
        #pragma unroll
        for (int off = 1; off < 64; off <<= 1) {
            uint32_t t = (uint32_t)__shfl_down((int)T, off, 64);
            if (lane + off < 64) T += t;
        }
        uint32_t Tex = T - s0;   // sum over lanes > lane
        uint32_t S0 = Tex + s0, S1 = Tex + s1, S2 = Tex + s2, S3 = Tex + s3;
        int b = -1; uint32_t sn = 0;
        if (S3 >= remr)      { b = 3; sn = S3 - vv[3]; }
        else if (S2 >= remr) { b = 2; sn = S2 - vv[2]; }
        else if (S1 >= remr) { b = 1; sn = S1 - vv[1]; }
        else if (S0 >= remr) { b = 0; sn = S0 - vv[0]; }
        uint32_t pk = (b >= 0) ? ((((uint32_t)(4 * lane + b + 1)) << 16) | sn) : 0u;
        #pragma unroll
        for (int off = 1; off < 64; off <<= 1) {
            uint32_t o = (uint32_t)__shfl_xor((int)pk, off, 64);
            pk = pk > o ? pk : o;
        }
        remr -= (pk & 0xFFFFu);
        return pk;
    };

    uint32_t remA = k, remB = k;
    const uint32_t pkA = scan_row(s_hist, remA);
    const uint32_t pkB = scan_row(s_hist + NHW, remB);
    const uint32_t dselA = (pkA >> 16) - 1u;
    const uint32_t dselB = (pkB >> 16) - 1u;
    bool fbA = (pkA == 0u) || (dselA == 255u);   // block-uniform (replicated scan)
    bool fbB = (pkB == 0u) || (dselB == 255u);
    const uint32_t hiA = 0x3F80u + dselA;
    const uint32_t hiB = 0x3F80u + dselB;

    // scatter survivors of the selected hi16 bin (order irrelevant); may include
    // a few sub-T0 elements in [1.09375, T0) — all strictly below every
    // histogrammed member, and rem <= member count, so rank is unaffected.
    #pragma unroll
    for (int e = 0; e < 16; ++e) {
        uint32_t ua = __float_as_uint(xbA[e]);
        if (!fbA && (ua >> 16) == hiA) {
            uint32_t pos = atomicAdd(&s_m2[0], 1u);
            if (pos < SURV_CAP) s_cand[0][pos] = ua;
        }
        uint32_t ub = __float_as_uint(xbB[e]);
        if (!fbB && (ub >> 16) == hiB) {
            uint32_t pos = atomicAdd(&s_m2[1], 1u);
            if (pos < SURV_CAP) s_cand[1][pos] = ub;
        }
    }
    __syncthreads();
    const uint32_t m2A = s_m2[0];   // block-uniform
    const uint32_t m2B = s_m2[1];

    // replicated 16-bit ballot descent: every wave loads the same survivors,
    // so every wave's ballot counts are the global counts.
    auto descent = [&](uint32_t hi16, const uint32_t* cand, uint32_t m2,
                       uint32_t rem) -> float {
        uint32_t cv = ((uint32_t)lane < m2) ? cand[lane] : ((~hi16) << 16);
        uint32_t cur = 0;
        #pragma unroll
        for (int bpos = 15; bpos >= 0; --bpos) {
            uint32_t t  = (hi16 << 16) | cur | (1u << bpos);
            uint32_t mk = ~((1u << bpos) - 1u);
            uint32_t c  = (uint32_t)__popcll(__ballot(((cv ^ t) & mk) == 0u));
            if (c >= rem) cur |= (1u << bpos);
            else          rem -= c;
        }
        return __uint_as_float((hi16 << 16) | cur);
    };

    float thrA = 0.0f, thrB = 0.0f;
    if (!fbA) { if (m2A <= SURV_CAP) thrA = descent(hiA, s_cand[0], m2A, remA); else fbA = true; }
    if (!fbB) { if (m2B <= SURV_CAP) thrB = descent(hiB, s_cand[1], m2B, remB); else fbB = true; }

    // adversarial-data fallback: exact 4-pass orderable radix (block-uniform entry)
    auto fallback_row = [&](const float* xb) -> float {
        __syncthreads();
        {
            uint4* h4 = (uint4*)s_hist;
            uint4 z; z.x = z.y = z.z = z.w = 0u;
            #pragma unroll
            for (int j = 0; j < 3; ++j) h4[tid + j * TPB] = z;  // region 0 only
        }
        __syncthreads();
        uint32_t prefix = 0, rem = k;
        const uint32_t pmasks[4] = {0u, 0xFF000000u, 0xFFFF0000u, 0xFFFFFF00u};
        #pragma unroll 1
        for (int pass = 0; pass < 4; ++pass) {
            const int shift = 24 - pass * 8;
            const uint32_t pm = pmasks[pass];
            #pragma unroll
            for (int e = 0; e < 16; ++e) {
                uint32_t ou = orderable(__float_as_uint(xb[e]));
                if (((ou ^ prefix) & pm) == 0u)
                    atomicAdd(&s_hist[((ou >> shift) & 255u) * HSTR + copy], 1u);
            }
            __syncthreads();
            {
                uint4 a  = *(const uint4*)&s_hist[tid * HSTR];
                uint4 b2 = *(const uint4*)&s_hist[tid * HSTR + 4];
                uint4 z; z.x = z.y = z.z = z.w = 0u;
                *(uint4*)&s_hist[tid * HSTR]     = z;
                *(uint4*)&s_hist[tid * HSTR + 4] = z;
                s_cnt[tid] = a.x + a.y + a.z + a.w + b2.x + b2.y + b2.z + b2.w;
            }
            __syncthreads();
            uint4 v = ((const uint4*)s_cnt)[lane];
            uint32_t s3 = v.w, s2 = v.z + s3, s1 = v.y + s2, s0 = v.x + s1;
            uint32_t T = s0;
            #pragma unroll
            for (int off = 1; off < 64; off <<= 1) {
                uint32_t t = (uint32_t)__shfl_down((int)T, off, 64);
                if (lane + off < 64) T += t;
            }
            uint32_t Tex = T - s0;
            uint32_t S0 = Tex + s0, S1 = Tex + s1, S2 = Tex + s2, S3 = Tex + s3;
            int b = -1; uint32_t sn = 0;
            if (S3 >= rem)      { b = 3; sn = S3 - v.w; }
            else if (S2 >= rem) { b = 2; sn = S2 - v.z; }
            else if (S1 >= rem) { b = 1; sn = S1 - v.y; }
            else if (S0 >= rem) { b = 0; sn = S0 - v.x; }
            uint32_t pk = (b >= 0) ? ((((uint32_t)(4 * lane + b + 1)) << 16) | sn) : 0u;
            #pragma unroll
            for (int off = 1; off < 64; off <<= 1) {
                uint32_t o = (uint32_t)__shfl_xor((int)pk, off, 64);
                pk = pk > o ? pk : o;
            }
            prefix |= ((pk >> 16) - 1u) << shift;
            rem -= (pk & 0xFFFFu);
        }
        uint32_t tu = (prefix & 0x80000000u) ? (prefix & 0x7FFFFFFFu) : ~prefix;
        return __uint_as_float(tu);
    };

    if (fbA) thrA = fallback_row(xbA);
    if (fbB) thrB = fallback_row(xbB);

    // epilogue: reload x (cache-hot), mask from boosted regs, nontemporal store
    #pragma unroll
    for (int j = 0; j < 4; ++j) {
        float4 a = xrA[tid + j * TPB];
        float4 o;
        o.x = (xbA[4*j+0] >= thrA) ? a.x : 0.0f;
        o.y = (xbA[4*j+1] >= thrA) ? a.y : 0.0f;
        o.z = (xbA[4*j+2] >= thrA) ? a.z : 0.0f;
        o.w = (xbA[4*j+3] >= thrA) ? a.w : 0.0f;
        store_nt(&orowA[tid + j * TPB], o);
    }
    if (validB) {
        #pragma unroll
        for (int j = 0; j < 4; ++j) {
            float4 c = xrB[tid + j * TPB];
            float4 o;
            o.x = (xbB[4*j+0] >= thrB) ? c.x : 0.0f;
            o.y = (xbB[4*j+1] >= thrB) ? c.y : 0.0f;
            o.z = (xbB[4*j+2] >= thrB) ? c.z : 0.0f;
            o.w = (xbB[4*j+3] >= thrB) ? c.w : 0.0f;
            store_nt(&orowB[tid + j * TPB], o);
        }
    }
}

extern "C" void kernel_launch(void* const* d_in, const int* in_sizes, int n_in,
                              void* d_out, int out_size, void* d_ws, size_t ws_size,
                              hipStream_t stream) {
    const float* x  = (const float*)d_in[0];
    const float* dc = (const float*)d_in[1];
    const int*   kp = (const int*)d_in[2];
    float* out = (float*)d_out;
    float* bf  = (float*)d_ws;                 // 4096 floats of scratch

    const int n    = in_sizes[1];              // 4096
    const int rows = in_sizes[0] / n;          // 8192

    boost_kernel<<<(n + TPB - 1) / TPB, TPB, 0, stream>>>(dc, kp, bf);
    kwinner_kernel<<<(rows + 1) / 2, TPB, 0, stream>>>(x, bf, kp, out, rows);
}